// Round 19
// baseline (35.968 us; speedup 1.0000x reference)
//
#include <hip/hip_runtime.h>
#include <math.h>

#define HW_ 1024

typedef __attribute__((ext_vector_type(4))) float   f32x4;
typedef __attribute__((ext_vector_type(8))) short   s16x8;

__device__ __forceinline__ unsigned bf16rne(float x) {
  unsigned u = __builtin_bit_cast(unsigned, x);
  u += 0x7FFF + ((u >> 16) & 1);
  return u >> 16;
}
__device__ __forceinline__ float bf2f(ushort u) {
  return __builtin_bit_cast(float, (unsigned)u << 16);
}

__device__ __forceinline__ void store_qkv(int qc, const float av[4],
    ushort* __restrict__ qbf, ushort* __restrict__ kbf, ushort* __restrict__ vtg,
    int b, int p)
{
  if (qc < 64) {
    const float SC = 0.35355339059327373f * 1.4426950408889634f;  // dkh^-0.5 * log2e
    int n = qc >> 3, d = qc & 7, bn = b * 8 + n;
    #pragma unroll
    for (int i = 0; i < 4; ++i)
      qbf[((size_t)bn * HW_ + p + i) * 8 + d] = (ushort)bf16rne(av[i] * SC);
  } else if (qc < 128) {
    int kc = qc - 64, n = kc >> 3, d = kc & 7, bn = b * 8 + n;
    #pragma unroll
    for (int i = 0; i < 4; ++i)
      kbf[((size_t)bn * HW_ + p + i) * 8 + d] = (ushort)bf16rne(av[i]);
  } else {
    int vc = qc - 128, n = vc >> 3, d = vc & 7, bn = b * 8 + n;
    #pragma unroll
    for (int i = 0; i < 4; ++i)
      vtg[((size_t)bn * 8 + d) * HW_ + p + i] = (ushort)bf16rne(av[i]);
  }
}

// ---------------- K1: qkv staging conv only (conv_out moved to K3) ----------------
// grid 768 = b(4) x ocp(24) x pt(8); 256 thr = 4 ocg x [2 ci-halves x 32 p-quads]
__global__ __launch_bounds__(256) void k_convs(
    const float* __restrict__ x, const float* __restrict__ w_qkv, const float* __restrict__ b_qkv,
    ushort* __restrict__ qbf, ushort* __restrict__ kbf, ushort* __restrict__ vtg)
{
  int bid = blockIdx.x;
  int pt  = bid & 7;
  int rest = bid >> 3;
  int ocp = rest % 24;
  int b   = rest / 24;
  int tid = threadIdx.x;
  int lane = tid & 63;
  int qc0 = ocp * 8 + (tid >> 6) * 2;      // 0..190 even; pair within one region
  int qc1 = qc0 + 1;
  int hf  = lane >> 5;                     // ci half
  int p   = pt * 128 + (lane & 31) * 4;
  int ci0 = hf * 32;

  const float* wrow0 = w_qkv + qc0 * 64 + ci0;
  const float* wrow1 = w_qkv + qc1 * 64 + ci0;
  float bias0 = b_qkv[qc0], bias1 = b_qkv[qc1];

  float4 a0 = make_float4(0.f, 0.f, 0.f, 0.f);
  float4 a1 = make_float4(0.f, 0.f, 0.f, 0.f);
  const float* xb = x + (size_t)b * 64 * HW_ + (size_t)ci0 * HW_ + p;
  #pragma unroll 16
  for (int ci = 0; ci < 32; ++ci) {
    float4 xv = *(const float4*)(xb + (size_t)ci * HW_);
    float w0 = wrow0[ci], w1 = wrow1[ci];
    a0.x = fmaf(w0, xv.x, a0.x); a1.x = fmaf(w1, xv.x, a1.x);
    a0.y = fmaf(w0, xv.y, a0.y); a1.y = fmaf(w1, xv.y, a1.y);
    a0.z = fmaf(w0, xv.z, a0.z); a1.z = fmaf(w1, xv.z, a1.z);
    a0.w = fmaf(w0, xv.w, a0.w); a1.w = fmaf(w1, xv.w, a1.w);
  }
  a0.x += __shfl_xor(a0.x, 32); a1.x += __shfl_xor(a1.x, 32);
  a0.y += __shfl_xor(a0.y, 32); a1.y += __shfl_xor(a1.y, 32);
  a0.z += __shfl_xor(a0.z, 32); a1.z += __shfl_xor(a1.z, 32);
  a0.w += __shfl_xor(a0.w, 32); a1.w += __shfl_xor(a1.w, 32);

  if (hf == 0) {
    float av0[4] = {a0.x + bias0, a0.y + bias0, a0.z + bias0, a0.w + bias0};
    float av1[4] = {a1.x + bias1, a1.y + bias1, a1.z + bias1, a1.w + bias1};
    store_qkv(qc0, av0, qbf, kbf, vtg, b, p);
    store_qkv(qc1, av1, qbf, kbf, vtg, b, p);
  }
}

// ---------------- K2: MFMA flash attention (R18-verbatim) ----------------
// grid 512 = bn(32) x qt(16); 512 thr = 8 waves: qsub(4) x key-half(2)
__global__ __launch_bounds__(512, 4) void k_attn(
    const ushort* __restrict__ qbf, const ushort* __restrict__ kbf, const ushort* __restrict__ vtg,
    const float* __restrict__ rel_h, const float* __restrict__ rel_w,
    float* __restrict__ aws)
{
  __shared__ ushort rhd[64 * 36];        // bf16, stride 36
  __shared__ ushort rwd[64 * 36];
  __shared__ ushort P_lds[8][16][128];   // per-wave [q][key], 256B rows, XOR-swizzled
  __shared__ __align__(16) ushort K_lds[1024 * 8];  // whole head's K, [key][d], 16KB
  __shared__ __align__(16) ushort V_lds[1024 * 8];  // whole head's V^T, swizzled, 16KB
  __shared__ float lbuf[4][16];
  __shared__ float obuf[4][16][8];

  int bid = blockIdx.x;
  int qt = bid & 15;
  int bn = bid >> 4;
  int b = bn >> 3, n = bn & 7;
  int tid = threadIdx.x;
  int lane = tid & 63;
  int w = tid >> 6;
  int qsub = w & 3, half = w >> 2;

  {
    const uint4* ksrc = (const uint4*)(kbf + (size_t)bn * HW_ * 8);
    const uint4* vsrc = (const uint4*)(vtg + (size_t)bn * 8 * HW_);
    uint4* kdst = (uint4*)K_lds;
    uint4* vdst = (uint4*)V_lds;
    kdst[tid]       = ksrc[tid];
    kdst[tid + 512] = ksrc[tid + 512];
    int g0 = tid, g1 = tid + 512;
    vdst[(g0 & ~127) | ((g0 & 127) ^ ((g0 >> 7) & 7))] = vsrc[g0];
    vdst[(g1 & ~127) | ((g1 & 127) ^ ((g1 >> 7) & 7))] = vsrc[g1];
  }

  {
    int qr = tid >> 3, qu = tid & 7;
    const ushort* qp = qbf + ((size_t)bn * HW_ + qt * 64 + qr) * 8;
    float qf[8];
    #pragma unroll
    for (int d = 0; d < 8; ++d) qf[d] = bf2f(qp[d]);
    int h = (qt * 64 + qr) >> 5, ww = qr & 31;
    #pragma unroll
    for (int s = 0; s < 4; ++s) {
      int idx = qu * 4 + s;
      const float* rp = rel_h + (idx - h + 31) * 8;
      float a = 0.f;
      #pragma unroll
      for (int d = 0; d < 8; ++d) a = fmaf(qf[d], rp[d], a);
      rhd[qr * 36 + idx] = (ushort)bf16rne(a);
      const float* rq = rel_w + (idx - ww + 31) * 8;
      float c = 0.f;
      #pragma unroll
      for (int d = 0; d < 8; ++d) c = fmaf(qf[d], rq[d], c);
      rwd[qr * 36 + idx] = (ushort)bf16rne(c);
    }
  }
  __syncthreads();

  int q = lane & 15, g = lane >> 4;
  int qr = qsub * 16 + q;

  s16x8 qfrag = {0,0,0,0,0,0,0,0};
  if (lane < 16)
    qfrag = *(const s16x8*)(qbf + ((size_t)bn * HW_ + qt * 64 + qsub * 16 + lane) * 8);

  float rw2[2][4];
  #pragma unroll
  for (int r = 0; r < 4; ++r) {
    rw2[0][r] = bf2f(rwd[qr * 36 + g * 4 + r]);
    rw2[1][r] = bf2f(rwd[qr * 36 + 16 + g * 4 + r]);
  }

  s16x8 vone;
  #pragma unroll
  for (int e = 0; e < 8; ++e) vone[e] = (short)0x3F80;   // bf16 1.0
  s16x8 vzero = {0,0,0,0,0,0,0,0};

  f32x4 O = {0.f, 0.f, 0.f, 0.f};

  char* prow = (char*)&P_lds[w][0][0] + q * 256;
  int sw = (q & 7) << 4;

  #pragma unroll
  for (int bki = 0; bki < 4; ++bki) {
    int bk = half * 4 + bki;
    float rh4[4];
    #pragma unroll
    for (int j = 0; j < 4; ++j) rh4[j] = bf2f(rhd[qr * 36 + bk * 4 + j]);

    f32x4 s[8];
    __builtin_amdgcn_s_setprio(1);
    #pragma unroll
    for (int t = 0; t < 8; ++t) {
      f32x4 c;
      #pragma unroll
      for (int r = 0; r < 4; ++r) c[r] = rh4[t >> 1] + rw2[t & 1][r];
      s16x8 kf = {0,0,0,0,0,0,0,0};
      if (lane < 16)
        kf = *(const s16x8*)(K_lds + (size_t)(bk * 128 + t * 16 + lane) * 8);
      s[t] = __builtin_amdgcn_mfma_f32_16x16x32_bf16(kf, qfrag, c, 0, 0, 0);
    }
    __builtin_amdgcn_s_setprio(0);

    s16x8 vfr[4];
    #pragma unroll
    for (int km = 0; km < 4; ++km) {
      if (q < 8)
        vfr[km] = *(const s16x8*)((const char*)V_lds + q * 2048 +
                                  (((bk * 16 + km * 4 + g) ^ q) << 4));
      else if (q == 8) vfr[km] = vone;
      else             vfr[km] = vzero;
    }

    #pragma unroll
    for (int t = 0; t < 8; ++t)
      #pragma unroll
      for (int r = 0; r < 4; ++r)
        s[t][r] = __builtin_amdgcn_exp2f(s[t][r]);

    #pragma unroll
    for (int t = 0; t < 8; ++t) {
      unsigned w0, w1;
      asm("v_cvt_pk_bf16_f32 %0, %1, %2" : "=v"(w0) : "v"(s[t][0]), "v"(s[t][1]));
      asm("v_cvt_pk_bf16_f32 %0, %1, %2" : "=v"(w1) : "v"(s[t][2]), "v"(s[t][3]));
      *(uint2*)(prow + (((t * 32 + g * 8) ^ sw))) = make_uint2(w0, w1);
    }
    asm volatile("" ::: "memory");

    __builtin_amdgcn_s_setprio(1);
    #pragma unroll
    for (int km = 0; km < 4; ++km) {
      s16x8 pfrag = *(const s16x8*)(prow + ((km * 64 + g * 16) ^ sw));
      O = __builtin_amdgcn_mfma_f32_16x16x32_bf16(vfr[km], pfrag, O, 0, 0, 0);
    }
    __builtin_amdgcn_s_setprio(0);
    asm volatile("" ::: "memory");
  }

  float l = __shfl(O[0], 32 + q);

  if (half == 1) {
    if (g < 2) {
      #pragma unroll
      for (int r = 0; r < 4; ++r) obuf[qsub][q][g * 4 + r] = O[r];
    }
    if (lane < 16) lbuf[qsub][lane] = l;
  }
  __syncthreads();
  if (half == 0 && g < 2) {
    float inv = 1.f / (l + lbuf[qsub][q]);
    int qrow = qt * 64 + qsub * 16 + q;
    float* ap = aws + ((size_t)b * 64 + n * 8) * HW_;
    #pragma unroll
    for (int r = 0; r < 4; ++r)
      ap[(size_t)(g * 4 + r) * HW_ + qrow] = (O[r] + obuf[qsub][q][g * 4 + r]) * inv;
  }
}

// ---------------- K3: output convs — attn-conv (og<16) + conv_out (og>=16) ----------------
// grid 1024 = b(4) x og(32) x pt(8); 256 thr = 4 oc x [2 ci-halves x 32 p-quads]
__global__ __launch_bounds__(256) void k_outconv(
    const float* __restrict__ aws, const float* __restrict__ x,
    const float* __restrict__ w_attn, const float* __restrict__ b_attn,
    const float* __restrict__ w_conv, const float* __restrict__ b_conv,
    float* __restrict__ out)
{
  int bid = blockIdx.x;
  int pt  = bid & 7;
  int og  = (bid >> 3) & 31;
  int b   = bid >> 8;
  int tid = threadIdx.x;
  int lane = tid & 63;
  int ocl = (og & 15) * 4 + (tid >> 6);
  bool isattn = og < 16;
  int hf  = lane >> 5;
  int p   = pt * 128 + (lane & 31) * 4;
  int ci0 = hf * 32;

  const float* src  = (isattn ? aws : x) + (size_t)b * 64 * HW_ + (size_t)ci0 * HW_ + p;
  const float* wrow = (isattn ? w_attn : w_conv) + ocl * 64 + ci0;
  float bias = (isattn ? b_attn : b_conv)[ocl];
  int outch = isattn ? (64 + ocl) : ocl;

  float4 acc = make_float4(0.f, 0.f, 0.f, 0.f);
  #pragma unroll 16
  for (int ci = 0; ci < 32; ++ci) {
    float wv = wrow[ci];
    float4 a4 = *(const float4*)(src + (size_t)ci * HW_);
    acc.x = fmaf(wv, a4.x, acc.x);
    acc.y = fmaf(wv, a4.y, acc.y);
    acc.z = fmaf(wv, a4.z, acc.z);
    acc.w = fmaf(wv, a4.w, acc.w);
  }
  acc.x += __shfl_xor(acc.x, 32);
  acc.y += __shfl_xor(acc.y, 32);
  acc.z += __shfl_xor(acc.z, 32);
  acc.w += __shfl_xor(acc.w, 32);
  if (hf == 0) {
    float4 r = make_float4(acc.x + bias, acc.y + bias, acc.z + bias, acc.w + bias);
    *(float4*)(out + ((size_t)b * 128 + outch) * HW_ + p) = r;
  }
}

extern "C" void kernel_launch(void* const* d_in, const int* in_sizes, int n_in,
                              void* d_out, int out_size, void* d_ws, size_t ws_size,
                              hipStream_t stream) {
  const float* x        = (const float*)d_in[0];
  const float* w_conv   = (const float*)d_in[1];
  const float* b_conv   = (const float*)d_in[2];
  const float* w_qkv    = (const float*)d_in[3];
  const float* b_qkv    = (const float*)d_in[4];
  const float* w_attn   = (const float*)d_in[5];
  const float* b_attn   = (const float*)d_in[6];
  const float* rel_h    = (const float*)d_in[7];
  const float* rel_w    = (const float*)d_in[8];
  float* out = (float*)d_out;

  float*  ws  = (float*)d_ws;
  float*  aws = ws;                               // [4][64][1024] f32 (1MB)
  ushort* qbf = (ushort*)(ws + 262144);           // [32][1024][8] bf16 (512KB)
  ushort* kbf = qbf + 262144;                     // [32][1024][8] bf16 (512KB)
  ushort* vtg = kbf + 262144;                     // [32][8][1024] bf16 (512KB)

  k_convs<<<768, 256, 0, stream>>>(x, w_qkv, b_qkv, qbf, kbf, vtg);
  k_attn<<<512, 512, 0, stream>>>(qbf, kbf, vtg, rel_h, rel_w, aws);
  k_outconv<<<1024, 256, 0, stream>>>(aws, x, w_attn, b_attn, w_conv, b_conv, out);
}

// Round 20
// 35.120 us; speedup vs baseline: 1.0241x; 1.0241x over previous
//
#include <hip/hip_runtime.h>
#include <math.h>

#define HW_ 1024

typedef __attribute__((ext_vector_type(4))) float   f32x4;
typedef __attribute__((ext_vector_type(8))) short   s16x8;

__device__ __forceinline__ unsigned bf16rne(float x) {
  unsigned u = __builtin_bit_cast(unsigned, x);
  u += 0x7FFF + ((u >> 16) & 1);
  return u >> 16;
}
__device__ __forceinline__ float bf2f(ushort u) {
  return __builtin_bit_cast(float, (unsigned)u << 16);
}

__device__ __forceinline__ void store_qkv(int qc, const float av[4],
    ushort* __restrict__ qbf, ushort* __restrict__ kbf, ushort* __restrict__ vtg,
    int b, int p)
{
  if (qc < 64) {
    const float SC = 0.35355339059327373f * 1.4426950408889634f;  // dkh^-0.5 * log2e
    int n = qc >> 3, d = qc & 7, bn = b * 8 + n;
    #pragma unroll
    for (int i = 0; i < 4; ++i)
      qbf[((size_t)bn * HW_ + p + i) * 8 + d] = (ushort)bf16rne(av[i] * SC);
  } else if (qc < 128) {
    int kc = qc - 64, n = kc >> 3, d = kc & 7, bn = b * 8 + n;
    #pragma unroll
    for (int i = 0; i < 4; ++i)
      kbf[((size_t)bn * HW_ + p + i) * 8 + d] = (ushort)bf16rne(av[i]);
  } else {
    int vc = qc - 128, n = vc >> 3, d = vc & 7, bn = b * 8 + n;
    #pragma unroll
    for (int i = 0; i < 4; ++i)
      vtg[((size_t)bn * 8 + d) * HW_ + p + i] = (ushort)bf16rne(av[i]);
  }
}

// ---------------- K1: qkv staging conv only (conv_out in K3) ----------------
// grid 768 = b(4) x ocp(24) x pt(8); 256 thr = 4 ocg x [2 ci-halves x 32 p-quads]
__global__ __launch_bounds__(256) void k_convs(
    const float* __restrict__ x, const float* __restrict__ w_qkv, const float* __restrict__ b_qkv,
    ushort* __restrict__ qbf, ushort* __restrict__ kbf, ushort* __restrict__ vtg)
{
  int bid = blockIdx.x;
  int pt  = bid & 7;
  int rest = bid >> 3;
  int ocp = rest % 24;
  int b   = rest / 24;
  int tid = threadIdx.x;
  int lane = tid & 63;
  int qc0 = ocp * 8 + (tid >> 6) * 2;      // 0..190 even; pair within one region
  int qc1 = qc0 + 1;
  int hf  = lane >> 5;                     // ci half
  int p   = pt * 128 + (lane & 31) * 4;
  int ci0 = hf * 32;

  const float* wrow0 = w_qkv + qc0 * 64 + ci0;
  const float* wrow1 = w_qkv + qc1 * 64 + ci0;
  float bias0 = b_qkv[qc0], bias1 = b_qkv[qc1];

  float4 a0 = make_float4(0.f, 0.f, 0.f, 0.f);
  float4 a1 = make_float4(0.f, 0.f, 0.f, 0.f);
  const float* xb = x + (size_t)b * 64 * HW_ + (size_t)ci0 * HW_ + p;
  #pragma unroll 16
  for (int ci = 0; ci < 32; ++ci) {
    float4 xv = *(const float4*)(xb + (size_t)ci * HW_);
    float w0 = wrow0[ci], w1 = wrow1[ci];
    a0.x = fmaf(w0, xv.x, a0.x); a1.x = fmaf(w1, xv.x, a1.x);
    a0.y = fmaf(w0, xv.y, a0.y); a1.y = fmaf(w1, xv.y, a1.y);
    a0.z = fmaf(w0, xv.z, a0.z); a1.z = fmaf(w1, xv.z, a1.z);
    a0.w = fmaf(w0, xv.w, a0.w); a1.w = fmaf(w1, xv.w, a1.w);
  }
  a0.x += __shfl_xor(a0.x, 32); a1.x += __shfl_xor(a1.x, 32);
  a0.y += __shfl_xor(a0.y, 32); a1.y += __shfl_xor(a1.y, 32);
  a0.z += __shfl_xor(a0.z, 32); a1.z += __shfl_xor(a1.z, 32);
  a0.w += __shfl_xor(a0.w, 32); a1.w += __shfl_xor(a1.w, 32);

  if (hf == 0) {
    float av0[4] = {a0.x + bias0, a0.y + bias0, a0.z + bias0, a0.w + bias0};
    float av1[4] = {a1.x + bias1, a1.y + bias1, a1.z + bias1, a1.w + bias1};
    store_qkv(qc0, av0, qbf, kbf, vtg, b, p);
    store_qkv(qc1, av1, qbf, kbf, vtg, b, p);
  }
}

// ---------------- K2: MFMA flash attention (R18 + qfrag hoist + coalesced aws write) ----------------
// grid 512 = bn(32) x qt(16); 512 thr = 8 waves: qsub(4) x key-half(2)
__global__ __launch_bounds__(512, 4) void k_attn(
    const ushort* __restrict__ qbf, const ushort* __restrict__ kbf, const ushort* __restrict__ vtg,
    const float* __restrict__ rel_h, const float* __restrict__ rel_w,
    float* __restrict__ aws)
{
  __shared__ ushort rhd[64 * 36];        // bf16, stride 36
  __shared__ ushort rwd[64 * 36];
  __shared__ ushort P_lds[8][16][128];   // per-wave [q][key], 256B rows, XOR-swizzled
  __shared__ __align__(16) ushort K_lds[1024 * 8];  // whole head's K, [key][d], 16KB
  __shared__ __align__(16) ushort V_lds[1024 * 8];  // whole head's V^T, swizzled, 16KB
  __shared__ float lbuf[4][16];
  __shared__ float obuf[4][16][8];

  int bid = blockIdx.x;
  int qt = bid & 15;
  int bn = bid >> 4;
  int b = bn >> 3, n = bn & 7;
  int tid = threadIdx.x;
  int lane = tid & 63;
  int w = tid >> 6;
  int qsub = w & 3, half = w >> 2;
  int q = lane & 15, g = lane >> 4;
  int qr = qsub * 16 + q;

  // ---- qfrag load hoisted above staging (latency overlaps the LDS fill)
  s16x8 qfrag = {0,0,0,0,0,0,0,0};
  if (lane < 16)
    qfrag = *(const s16x8*)(qbf + ((size_t)bn * HW_ + qt * 64 + qsub * 16 + lane) * 8);

  // ---- stage K and V into LDS (coalesced; V LDS-dst swizzled: unit ^= d&7)
  {
    const uint4* ksrc = (const uint4*)(kbf + (size_t)bn * HW_ * 8);
    const uint4* vsrc = (const uint4*)(vtg + (size_t)bn * 8 * HW_);
    uint4* kdst = (uint4*)K_lds;
    uint4* vdst = (uint4*)V_lds;
    kdst[tid]       = ksrc[tid];
    kdst[tid + 512] = ksrc[tid + 512];
    int g0 = tid, g1 = tid + 512;
    vdst[(g0 & ~127) | ((g0 & 127) ^ ((g0 >> 7) & 7))] = vsrc[g0];
    vdst[(g1 & ~127) | ((g1 & 127) ^ ((g1 >> 7) & 7))] = vsrc[g1];
  }

  // ---- build rel tables (bf16)
  {
    int qrr = tid >> 3, qu = tid & 7;
    const ushort* qp = qbf + ((size_t)bn * HW_ + qt * 64 + qrr) * 8;
    float qf[8];
    #pragma unroll
    for (int d = 0; d < 8; ++d) qf[d] = bf2f(qp[d]);
    int h = (qt * 64 + qrr) >> 5, ww = qrr & 31;
    #pragma unroll
    for (int s = 0; s < 4; ++s) {
      int idx = qu * 4 + s;
      const float* rp = rel_h + (idx - h + 31) * 8;
      float a = 0.f;
      #pragma unroll
      for (int d = 0; d < 8; ++d) a = fmaf(qf[d], rp[d], a);
      rhd[qrr * 36 + idx] = (ushort)bf16rne(a);
      const float* rq = rel_w + (idx - ww + 31) * 8;
      float c = 0.f;
      #pragma unroll
      for (int d = 0; d < 8; ++d) c = fmaf(qf[d], rq[d], c);
      rwd[qrr * 36 + idx] = (ushort)bf16rne(c);
    }
  }
  __syncthreads();

  float rw2[2][4];
  #pragma unroll
  for (int r = 0; r < 4; ++r) {
    rw2[0][r] = bf2f(rwd[qr * 36 + g * 4 + r]);
    rw2[1][r] = bf2f(rwd[qr * 36 + 16 + g * 4 + r]);
  }

  s16x8 vone;
  #pragma unroll
  for (int e = 0; e < 8; ++e) vone[e] = (short)0x3F80;   // bf16 1.0
  s16x8 vzero = {0,0,0,0,0,0,0,0};

  f32x4 O = {0.f, 0.f, 0.f, 0.f};

  char* prow = (char*)&P_lds[w][0][0] + q * 256;
  int sw = (q & 7) << 4;

  #pragma unroll
  for (int bki = 0; bki < 4; ++bki) {
    int bk = half * 4 + bki;
    float rh4[4];
    #pragma unroll
    for (int j = 0; j < 4; ++j) rh4[j] = bf2f(rhd[qr * 36 + bk * 4 + j]);

    f32x4 s[8];
    __builtin_amdgcn_s_setprio(1);
    #pragma unroll
    for (int t = 0; t < 8; ++t) {
      f32x4 c;
      #pragma unroll
      for (int r = 0; r < 4; ++r) c[r] = rh4[t >> 1] + rw2[t & 1][r];
      s16x8 kf = {0,0,0,0,0,0,0,0};
      if (lane < 16)
        kf = *(const s16x8*)(K_lds + (size_t)(bk * 128 + t * 16 + lane) * 8);
      s[t] = __builtin_amdgcn_mfma_f32_16x16x32_bf16(kf, qfrag, c, 0, 0, 0);
    }
    __builtin_amdgcn_s_setprio(0);

    s16x8 vfr[4];
    #pragma unroll
    for (int km = 0; km < 4; ++km) {
      if (q < 8)
        vfr[km] = *(const s16x8*)((const char*)V_lds + q * 2048 +
                                  (((bk * 16 + km * 4 + g) ^ q) << 4));
      else if (q == 8) vfr[km] = vone;
      else             vfr[km] = vzero;
    }

    #pragma unroll
    for (int t = 0; t < 8; ++t)
      #pragma unroll
      for (int r = 0; r < 4; ++r)
        s[t][r] = __builtin_amdgcn_exp2f(s[t][r]);

    #pragma unroll
    for (int t = 0; t < 8; ++t) {
      unsigned w0, w1;
      asm("v_cvt_pk_bf16_f32 %0, %1, %2" : "=v"(w0) : "v"(s[t][0]), "v"(s[t][1]));
      asm("v_cvt_pk_bf16_f32 %0, %1, %2" : "=v"(w1) : "v"(s[t][2]), "v"(s[t][3]));
      *(uint2*)(prow + (((t * 32 + g * 8) ^ sw))) = make_uint2(w0, w1);
    }
    asm volatile("" ::: "memory");

    __builtin_amdgcn_s_setprio(1);
    #pragma unroll
    for (int km = 0; km < 4; ++km) {
      s16x8 pfrag = *(const s16x8*)(prow + ((km * 64 + g * 16) ^ sw));
      O = __builtin_amdgcn_mfma_f32_16x16x32_bf16(vfr[km], pfrag, O, 0, 0, 0);
    }
    __builtin_amdgcn_s_setprio(0);
    asm volatile("" ::: "memory");
  }

  float l = __shfl(O[0], 32 + q);

  // ---- merge key-halves; finalize into obuf; coalesced float4 store to aws
  if (half == 1) {
    if (g < 2) {
      #pragma unroll
      for (int r = 0; r < 4; ++r) obuf[qsub][q][g * 4 + r] = O[r];
    }
    if (lane < 16) lbuf[qsub][lane] = l;
  }
  __syncthreads();
  if (half == 0 && g < 2) {
    float inv = 1.f / (l + lbuf[qsub][q]);
    #pragma unroll
    for (int r = 0; r < 4; ++r)
      obuf[qsub][q][g * 4 + r] = (O[r] + obuf[qsub][q][g * 4 + r]) * inv;
  }
  __syncthreads();
  if (tid < 128) {
    int d = tid >> 4, px4 = (tid & 15) * 4;
    int qsw = px4 >> 4, qw = px4 & 15;
    float4 v;
    v.x = obuf[qsw][qw + 0][d];
    v.y = obuf[qsw][qw + 1][d];
    v.z = obuf[qsw][qw + 2][d];
    v.w = obuf[qsw][qw + 3][d];
    *(float4*)(aws + ((size_t)b * 64 + n * 8 + d) * HW_ + qt * 64 + px4) = v;
  }
}

// ---------------- K3: output convs — attn-conv (og<16) + conv_out (og>=16) ----------------
// grid 1024 = b(4) x og(32) x pt(8); 256 thr = 4 oc x [2 ci-halves x 32 p-quads]
__global__ __launch_bounds__(256) void k_outconv(
    const float* __restrict__ aws, const float* __restrict__ x,
    const float* __restrict__ w_attn, const float* __restrict__ b_attn,
    const float* __restrict__ w_conv, const float* __restrict__ b_conv,
    float* __restrict__ out)
{
  int bid = blockIdx.x;
  int pt  = bid & 7;
  int og  = (bid >> 3) & 31;
  int b   = bid >> 8;
  int tid = threadIdx.x;
  int lane = tid & 63;
  int ocl = (og & 15) * 4 + (tid >> 6);
  bool isattn = og < 16;
  int hf  = lane >> 5;
  int p   = pt * 128 + (lane & 31) * 4;
  int ci0 = hf * 32;

  const float* src  = (isattn ? aws : x) + (size_t)b * 64 * HW_ + (size_t)ci0 * HW_ + p;
  const float* wrow = (isattn ? w_attn : w_conv) + ocl * 64 + ci0;
  float bias = (isattn ? b_attn : b_conv)[ocl];
  int outch = isattn ? (64 + ocl) : ocl;

  float4 acc = make_float4(0.f, 0.f, 0.f, 0.f);
  #pragma unroll 16
  for (int ci = 0; ci < 32; ++ci) {
    float wv = wrow[ci];
    float4 a4 = *(const float4*)(src + (size_t)ci * HW_);
    acc.x = fmaf(wv, a4.x, acc.x);
    acc.y = fmaf(wv, a4.y, acc.y);
    acc.z = fmaf(wv, a4.z, acc.z);
    acc.w = fmaf(wv, a4.w, acc.w);
  }
  acc.x += __shfl_xor(acc.x, 32);
  acc.y += __shfl_xor(acc.y, 32);
  acc.z += __shfl_xor(acc.z, 32);
  acc.w += __shfl_xor(acc.w, 32);
  if (hf == 0) {
    float4 r = make_float4(acc.x + bias, acc.y + bias, acc.z + bias, acc.w + bias);
    *(float4*)(out + ((size_t)b * 128 + outch) * HW_ + p) = r;
  }
}

extern "C" void kernel_launch(void* const* d_in, const int* in_sizes, int n_in,
                              void* d_out, int out_size, void* d_ws, size_t ws_size,
                              hipStream_t stream) {
  const float* x        = (const float*)d_in[0];
  const float* w_conv   = (const float*)d_in[1];
  const float* b_conv   = (const float*)d_in[2];
  const float* w_qkv    = (const float*)d_in[3];
  const float* b_qkv    = (const float*)d_in[4];
  const float* w_attn   = (const float*)d_in[5];
  const float* b_attn   = (const float*)d_in[6];
  const float* rel_h    = (const float*)d_in[7];
  const float* rel_w    = (const float*)d_in[8];
  float* out = (float*)d_out;

  float*  ws  = (float*)d_ws;
  float*  aws = ws;                               // [4][64][1024] f32 (1MB)
  ushort* qbf = (ushort*)(ws + 262144);           // [32][1024][8] bf16 (512KB)
  ushort* kbf = qbf + 262144;                     // [32][1024][8] bf16 (512KB)
  ushort* vtg = kbf + 262144;                     // [32][8][1024] bf16 (512KB)

  k_convs<<<768, 256, 0, stream>>>(x, w_qkv, b_qkv, qbf, kbf, vtg);
  k_attn<<<512, 512, 0, stream>>>(qbf, kbf, vtg, rel_h, rel_w, aws);
  k_outconv<<<1024, 256, 0, stream>>>(aws, x, w_attn, b_attn, w_conv, b_conv, out);
}